// Round 8
// baseline (32.771 us; speedup 1.0000x reference)
//
#include <hip/hip_runtime.h>
#include <math.h>

#define HH   512
#define WW   512
#define KG   256
#define NPIX (HH * WW)
#define EPSF 1e-6f
#define LOG2E 1.4426950408889634f

// Software exp2 built from 8 full-rate VALU ops (no trans-pipe use):
// n = rint(e); f = e-n in [-0.5,0.5]; 2^f by degree-4 poly; scale v_ldexp_f32
// (ldexp handles deep-negative n with proper flush). Rel err ~2e-6.
__device__ __forceinline__ float fast_exp2(float e) {
    const float fn = rintf(e);               // v_rndne_f32
    const float f  = e - fn;                 // v_sub_f32
    const int   n  = (int)fn;                // v_cvt_i32_f32
    float p = fmaf(f, 0.0096181291f, 0.0555041087f);
    p = fmaf(f, p, 0.2402265069f);
    p = fmaf(f, p, 0.6931471806f);
    p = fmaf(f, p, 1.0f);
    return __builtin_amdgcn_ldexpf(p, n);    // v_ldexp_f32
}

// R3 structure exactly: per-block fold of K=256 gaussians into LDS, 1 px per
// thread, 3 broadcast ds_read_b128 per gaussian. Only changes vs R3:
// soft exp2 (above) and unroll 4 (keeps live set < 128 VGPR; R6's unroll-8
// overflow was the suspected confound).
__global__ __launch_bounds__(256, 4) void gauss_render(
    const float* __restrict__ grid,          // (H,W,2)
    const float* __restrict__ mu,            // (K,2)
    const float* __restrict__ log_scales,    // (K,2)
    const float* __restrict__ theta,         // (K,)
    const float* __restrict__ color_logits,  // (K,3)
    const float* __restrict__ log_amp,       // (K,1)
    float* __restrict__ out)                 // (H,W,3)
{
    __shared__ float4 sp[3 * KG];   // 12 KB

    const int tid = threadIdx.x;
    {
        const int k = tid;                        // blockDim.x == KG == 256
        const float mx  = mu[2 * k + 0];
        const float my  = mu[2 * k + 1];
        const float sx  = expf(log_scales[2 * k + 0]);
        const float sy  = expf(log_scales[2 * k + 1]);
        const float isx = 1.0f / (sx * sx + EPSF);
        const float isy = 1.0f / (sy * sy + EPSF);
        const float t   = theta[k];
        const float c   = cosf(t);
        const float s   = sinf(t);

        const float A = c * c * isx + s * s * isy;
        const float B = s * s * isx + c * c * isy;
        const float C = 2.0f * c * s * (isx - isy);

        const float la  = log_amp[k];
        const float amp = (la > 20.0f) ? la : log1pf(expf(la));  // softplus
        const float lnA = logf(amp);

        const float ca = -0.5f * LOG2E * A;
        const float cb = -0.5f * LOG2E * B;
        const float cc = -0.5f * LOG2E * C;
        const float cd = LOG2E * (A * mx + 0.5f * C * my);
        const float ce = LOG2E * (B * my + 0.5f * C * mx);
        const float cf = LOG2E * (lnA - 0.5f * (A * mx * mx + B * my * my + C * mx * my));

        const float c0 = 1.0f / (1.0f + expf(-color_logits[3 * k + 0]));
        const float c1 = 1.0f / (1.0f + expf(-color_logits[3 * k + 1]));
        const float c2 = 1.0f / (1.0f + expf(-color_logits[3 * k + 2]));

        sp[3 * k + 0] = make_float4(ca, cb, cc, cd);
        sp[3 * k + 1] = make_float4(ce, cf, c0, c1);
        sp[3 * k + 2] = make_float4(c2, 0.0f, 0.0f, 0.0f);
    }
    __syncthreads();

    const int pix = blockIdx.x * 256 + tid;       // one pixel per thread

    const float2 p = reinterpret_cast<const float2*>(grid)[pix];
    const float X = p.x, Y = p.y;
    const float X2 = X * X, Y2 = Y * Y, XY = X * Y;

    float den = 0.f, R = 0.f, G = 0.f, B = 0.f;

    #pragma unroll 4
    for (int k = 0; k < KG; ++k) {
        const float4 q0 = sp[3 * k + 0];   // ca cb cc cd
        const float4 q1 = sp[3 * k + 1];   // ce cf c0 c1
        const float4 q2 = sp[3 * k + 2];   // c2 - - -

        float e = fmaf(q1.x, Y, q1.y);     // ce*y + cf
        e = fmaf(q0.w, X,  e);             // + cd*x
        e = fmaf(q0.z, XY, e);             // + cc*xy
        e = fmaf(q0.y, Y2, e);             // + cb*y^2
        e = fmaf(q0.x, X2, e);             // + ca*x^2

        const float w = fast_exp2(e);

        den += w;
        R = fmaf(w, q1.z, R);
        G = fmaf(w, q1.w, G);
        B = fmaf(w, q2.x, B);
    }

    const float inv = 1.0f / (den + EPSF);
    out[3 * pix + 0] = fminf(fmaxf(R * inv, 0.f), 1.f);
    out[3 * pix + 1] = fminf(fmaxf(G * inv, 0.f), 1.f);
    out[3 * pix + 2] = fminf(fmaxf(B * inv, 0.f), 1.f);
}

extern "C" void kernel_launch(void* const* d_in, const int* in_sizes, int n_in,
                              void* d_out, int out_size, void* d_ws, size_t ws_size,
                              hipStream_t stream) {
    const float* grid         = (const float*)d_in[0];
    const float* mu           = (const float*)d_in[1];
    const float* log_scales   = (const float*)d_in[2];
    const float* theta        = (const float*)d_in[3];
    const float* color_logits = (const float*)d_in[4];
    const float* log_amp      = (const float*)d_in[5];
    float* out = (float*)d_out;

    const int threads = 256;
    const int blocks  = NPIX / threads;          // 1024 blocks, 1 px/thread
    hipLaunchKernelGGL(gauss_render, dim3(blocks), dim3(threads), 0, stream,
                       grid, mu, log_scales, theta, color_logits, log_amp, out);
}

// Round 9
// 29.937 us; speedup vs baseline: 1.0947x; 1.0947x over previous
//
#include <hip/hip_runtime.h>
#include <hip/hip_fp16.h>
#include <math.h>

#define HH   512
#define WW   512
#define KG   256
#define NPIX (HH * WW)
#define EPSF 1e-6f
#define LOG2E 1.4426950408889634f

// R3 structure, params packed 48B -> 32B per gaussian (2x ds_read_b128/iter):
//   sp0[k] = {ca, cb, cc, cd}
//   sp1[k] = {ce, cf, bitcast(half2(c0,c1)), c2}
// log2(w_k(x,y)) = ca*x^2 + cb*y^2 + cc*xy + cd*x + ce*y + cf   (log2e folded)
// Poly evaluated in 3-deep Horner form (5 FMA, no precomputed x^2/y^2/xy).
__global__ __launch_bounds__(256, 4) void gauss_render(
    const float* __restrict__ grid,          // (H,W,2)
    const float* __restrict__ mu,            // (K,2)
    const float* __restrict__ log_scales,    // (K,2)
    const float* __restrict__ theta,         // (K,)
    const float* __restrict__ color_logits,  // (K,3)
    const float* __restrict__ log_amp,       // (K,1)
    float* __restrict__ out)                 // (H,W,3)
{
    __shared__ float4 sp0[KG];   // 4 KB
    __shared__ float4 sp1[KG];   // 4 KB

    const int tid = threadIdx.x;
    {
        const int k = tid;                        // blockDim.x == KG == 256
        const float mx  = mu[2 * k + 0];
        const float my  = mu[2 * k + 1];
        const float sx  = expf(log_scales[2 * k + 0]);
        const float sy  = expf(log_scales[2 * k + 1]);
        const float isx = 1.0f / (sx * sx + EPSF);
        const float isy = 1.0f / (sy * sy + EPSF);
        const float t   = theta[k];
        const float c   = cosf(t);
        const float s   = sinf(t);

        const float A = c * c * isx + s * s * isy;
        const float B = s * s * isx + c * c * isy;
        const float C = 2.0f * c * s * (isx - isy);

        const float la  = log_amp[k];
        const float amp = (la > 20.0f) ? la : log1pf(expf(la));  // softplus
        const float lnA = logf(amp);

        const float ca = -0.5f * LOG2E * A;
        const float cb = -0.5f * LOG2E * B;
        const float cc = -0.5f * LOG2E * C;
        const float cd = LOG2E * (A * mx + 0.5f * C * my);
        const float ce = LOG2E * (B * my + 0.5f * C * mx);
        const float cf = LOG2E * (lnA - 0.5f * (A * mx * mx + B * my * my + C * mx * my));

        const float c0 = 1.0f / (1.0f + expf(-color_logits[3 * k + 0]));
        const float c1 = 1.0f / (1.0f + expf(-color_logits[3 * k + 1]));
        const float c2 = 1.0f / (1.0f + expf(-color_logits[3 * k + 2]));

        const __half2 h01 = __floats2half2_rn(c0, c1);
        const float   hz  = __builtin_bit_cast(float, h01);

        sp0[k] = make_float4(ca, cb, cc, cd);
        sp1[k] = make_float4(ce, cf, hz, c2);
    }
    __syncthreads();

    const int pix = blockIdx.x * 256 + tid;       // one pixel per thread

    const float2 p = reinterpret_cast<const float2*>(grid)[pix];
    const float X = p.x, Y = p.y;

    float den = 0.f, R = 0.f, G = 0.f, B = 0.f;

    #pragma unroll 4
    for (int k = 0; k < KG; ++k) {
        const float4 q0 = sp0[k];   // ca cb cc cd
        const float4 q1 = sp1[k];   // ce cf h(c0,c1) c2

        // e = (ca*x + cc*y + cd)*x + (cb*y + ce)*y + cf   (3-deep, 5 FMA)
        const float t1 = fmaf(q0.z, Y, q0.w);      // cc*y + cd
        const float t2 = fmaf(q0.x, X, t1);        // ca*x + ^
        const float t3 = fmaf(q0.y, Y, q1.x);      // cb*y + ce
        const float t4 = fmaf(t3, Y, q1.y);        // ^*y + cf
        const float e  = fmaf(t2, X, t4);

        const float w = __builtin_amdgcn_exp2f(e);

        const __half2 h   = __builtin_bit_cast(__half2, q1.z);
        const float2  c01 = __half22float2(h);

        den += w;
        R = fmaf(w, c01.x, R);
        G = fmaf(w, c01.y, G);
        B = fmaf(w, q1.w, B);
    }

    const float inv = 1.0f / (den + EPSF);
    out[3 * pix + 0] = fminf(fmaxf(R * inv, 0.f), 1.f);
    out[3 * pix + 1] = fminf(fmaxf(G * inv, 0.f), 1.f);
    out[3 * pix + 2] = fminf(fmaxf(B * inv, 0.f), 1.f);
}

extern "C" void kernel_launch(void* const* d_in, const int* in_sizes, int n_in,
                              void* d_out, int out_size, void* d_ws, size_t ws_size,
                              hipStream_t stream) {
    const float* grid         = (const float*)d_in[0];
    const float* mu           = (const float*)d_in[1];
    const float* log_scales   = (const float*)d_in[2];
    const float* theta        = (const float*)d_in[3];
    const float* color_logits = (const float*)d_in[4];
    const float* log_amp      = (const float*)d_in[5];
    float* out = (float*)d_out;

    const int threads = 256;
    const int blocks  = NPIX / threads;          // 1024 blocks, 1 px/thread
    hipLaunchKernelGGL(gauss_render, dim3(blocks), dim3(threads), 0, stream,
                       grid, mu, log_scales, theta, color_logits, log_amp, out);
}

// Round 10
// 26.989 us; speedup vs baseline: 1.2143x; 1.1092x over previous
//
#include <hip/hip_runtime.h>
#include <math.h>

#define HH   512
#define WW   512
#define KG   256
#define NPIX (HH * WW)
#define EPSF 1e-6f
#define LOG2E 1.4426950408889634f

// 2 same-X pixels per thread. grid[i,j] = (xs[i], ys[j]) -> consecutive
// pixels share X, so  e = cb*y^2 + (cc*X+ce)*y + ((ca*X+cd)*X+cf)  lets the
// X-part (b0,b1) be computed once per pixel-pair:
//   per gaussian-iter: 7 FMA + 2 exp + 8 accum  (vs ~2x11 for two singles).
// Block = one image row (512 px, 256 threads); 512 blocks = 2 waves/SIMD
// (validated sufficient TLP: busy ~67% at >=2 waves/SIMD).
__global__ __launch_bounds__(256, 2) void gauss_render(
    const float* __restrict__ grid,          // (H,W,2)
    const float* __restrict__ mu,            // (K,2)
    const float* __restrict__ log_scales,    // (K,2)
    const float* __restrict__ theta,         // (K,)
    const float* __restrict__ color_logits,  // (K,3)
    const float* __restrict__ log_amp,       // (K,1)
    float* __restrict__ out)                 // (H,W,3)
{
    __shared__ float4 sp[3 * KG];   // 12 KB

    const int tid = threadIdx.x;
    {
        const int k = tid;                        // blockDim.x == KG == 256
        const float mx  = mu[2 * k + 0];
        const float my  = mu[2 * k + 1];
        const float sx  = expf(log_scales[2 * k + 0]);
        const float sy  = expf(log_scales[2 * k + 1]);
        const float isx = 1.0f / (sx * sx + EPSF);
        const float isy = 1.0f / (sy * sy + EPSF);
        const float t   = theta[k];
        const float c   = cosf(t);
        const float s   = sinf(t);

        const float A = c * c * isx + s * s * isy;
        const float B = s * s * isx + c * c * isy;
        const float C = 2.0f * c * s * (isx - isy);

        const float la  = log_amp[k];
        const float amp = (la > 20.0f) ? la : log1pf(expf(la));  // softplus
        const float lnA = logf(amp);

        const float ca = -0.5f * LOG2E * A;
        const float cb = -0.5f * LOG2E * B;
        const float cc = -0.5f * LOG2E * C;
        const float cd = LOG2E * (A * mx + 0.5f * C * my);
        const float ce = LOG2E * (B * my + 0.5f * C * mx);
        const float cf = LOG2E * (lnA - 0.5f * (A * mx * mx + B * my * my + C * mx * my));

        const float c0 = 1.0f / (1.0f + expf(-color_logits[3 * k + 0]));
        const float c1 = 1.0f / (1.0f + expf(-color_logits[3 * k + 1]));
        const float c2 = 1.0f / (1.0f + expf(-color_logits[3 * k + 2]));

        sp[3 * k + 0] = make_float4(ca, cb, cc, cd);
        sp[3 * k + 1] = make_float4(ce, cf, c0, c1);
        sp[3 * k + 2] = make_float4(c2, 0.0f, 0.0f, 0.0f);
    }
    __syncthreads();

    // Thread handles pixels p0 = 2*(blockIdx*256+tid), p1 = p0+1 (same X).
    const int pairIdx = blockIdx.x * 256 + tid;
    const int p0      = 2 * pairIdx;

    const float4 g4 = reinterpret_cast<const float4*>(grid)[pairIdx]; // {X,Y0,X,Y1}
    const float X  = g4.x;
    const float Y0 = g4.y;
    const float Y1 = g4.w;

    float den0 = 0.f, R0 = 0.f, G0 = 0.f, B0 = 0.f;
    float den1 = 0.f, R1 = 0.f, G1 = 0.f, B1 = 0.f;

    #pragma unroll 4
    for (int k = 0; k < KG; ++k) {
        const float4 q0 = sp[3 * k + 0];   // ca cb cc cd
        const float4 q1 = sp[3 * k + 1];   // ce cf c0 c1
        const float4 q2 = sp[3 * k + 2];   // c2 - - -

        const float b1 = fmaf(q0.z, X, q1.x);                 // cc*X + ce
        const float b0 = fmaf(fmaf(q0.x, X, q0.w), X, q1.y);  // (ca*X+cd)*X + cf

        const float e0 = fmaf(fmaf(q0.y, Y0, b1), Y0, b0);    // (cb*y0+b1)*y0 + b0
        const float e1 = fmaf(fmaf(q0.y, Y1, b1), Y1, b0);

        const float w0 = __builtin_amdgcn_exp2f(e0);
        const float w1 = __builtin_amdgcn_exp2f(e1);

        den0 += w0;                 den1 += w1;
        R0 = fmaf(w0, q1.z, R0);    R1 = fmaf(w1, q1.z, R1);
        G0 = fmaf(w0, q1.w, G0);    G1 = fmaf(w1, q1.w, G1);
        B0 = fmaf(w0, q2.x, B0);    B1 = fmaf(w1, q2.x, B1);
    }

    const float i0 = 1.0f / (den0 + EPSF);
    const float i1 = 1.0f / (den1 + EPSF);

    float2* o2 = reinterpret_cast<float2*>(out + 3 * p0);     // 24B, 8B-aligned
    o2[0] = make_float2(fminf(fmaxf(R0 * i0, 0.f), 1.f),
                        fminf(fmaxf(G0 * i0, 0.f), 1.f));
    o2[1] = make_float2(fminf(fmaxf(B0 * i0, 0.f), 1.f),
                        fminf(fmaxf(R1 * i1, 0.f), 1.f));
    o2[2] = make_float2(fminf(fmaxf(G1 * i1, 0.f), 1.f),
                        fminf(fmaxf(B1 * i1, 0.f), 1.f));
}

extern "C" void kernel_launch(void* const* d_in, const int* in_sizes, int n_in,
                              void* d_out, int out_size, void* d_ws, size_t ws_size,
                              hipStream_t stream) {
    const float* grid         = (const float*)d_in[0];
    const float* mu           = (const float*)d_in[1];
    const float* log_scales   = (const float*)d_in[2];
    const float* theta        = (const float*)d_in[3];
    const float* color_logits = (const float*)d_in[4];
    const float* log_amp      = (const float*)d_in[5];
    float* out = (float*)d_out;

    const int threads = 256;
    const int blocks  = NPIX / (threads * 2);    // 512 blocks, 2 px/thread
    hipLaunchKernelGGL(gauss_render, dim3(blocks), dim3(threads), 0, stream,
                       grid, mu, log_scales, theta, color_logits, log_amp, out);
}

// Round 11
// 24.573 us; speedup vs baseline: 1.3336x; 1.0983x over previous
//
#include <hip/hip_runtime.h>
#include <math.h>

#define HH   512
#define WW   512
#define KG   256
#define NPIX (HH * WW)
#define EPSF 1e-6f
#define LOG2E 1.4426950408889634f

// One block per image COLUMN (512 pixels sharing X). Setup phase folds the
// X-dependence of every gaussian into per-column coefficients in LDS:
//   b1[k] = cc*X + ce        b0[k] = (ca*X + cd)*X + cf
// so the inner loop per (pixel, gaussian) is just
//   e = (cb*Y + b1)*Y + b0 ;  w = exp2(e) ;  4 accum FMAs
// = 2 FMA + 1 exp + 4 FMA + 2 broadcast LDS reads (~10 wave-insts).
//   sA[k] = {b0, b1, cb, c0}   (ds_read_b128, wave-uniform broadcast)
//   sB[k] = {c1, c2}           (ds_read_b64,  wave-uniform broadcast)
__global__ __launch_bounds__(512, 4) void gauss_render(
    const float* __restrict__ grid,          // (H,W,2)
    const float* __restrict__ mu,            // (K,2)
    const float* __restrict__ log_scales,    // (K,2)
    const float* __restrict__ theta,         // (K,)
    const float* __restrict__ color_logits,  // (K,3)
    const float* __restrict__ log_amp,       // (K,1)
    float* __restrict__ out)                 // (H,W,3)
{
    __shared__ float4 sA[KG];   // 4 KB
    __shared__ float2 sB[KG];   // 2 KB

    const int tid = threadIdx.x;
    const int col = blockIdx.x;                  // column i
    const int pix = col * WW + tid;              // this thread's pixel

    const float2 p = reinterpret_cast<const float2*>(grid)[pix];
    const float X = p.x;                         // same for whole block
    const float Y = p.y;

    if (tid < KG) {
        const int k = tid;
        const float mx  = mu[2 * k + 0];
        const float my  = mu[2 * k + 1];
        const float sx  = expf(log_scales[2 * k + 0]);
        const float sy  = expf(log_scales[2 * k + 1]);
        const float isx = 1.0f / (sx * sx + EPSF);
        const float isy = 1.0f / (sy * sy + EPSF);
        const float t   = theta[k];
        const float c   = cosf(t);
        const float s   = sinf(t);

        const float A = c * c * isx + s * s * isy;
        const float B = s * s * isx + c * c * isy;
        const float C = 2.0f * c * s * (isx - isy);

        const float la  = log_amp[k];
        const float amp = (la > 20.0f) ? la : log1pf(expf(la));  // softplus
        const float lnA = logf(amp);

        const float ca = -0.5f * LOG2E * A;
        const float cb = -0.5f * LOG2E * B;
        const float cc = -0.5f * LOG2E * C;
        const float cd = LOG2E * (A * mx + 0.5f * C * my);
        const float ce = LOG2E * (B * my + 0.5f * C * mx);
        const float cf = LOG2E * (lnA - 0.5f * (A * mx * mx + B * my * my + C * mx * my));

        const float c0 = 1.0f / (1.0f + expf(-color_logits[3 * k + 0]));
        const float c1 = 1.0f / (1.0f + expf(-color_logits[3 * k + 1]));
        const float c2 = 1.0f / (1.0f + expf(-color_logits[3 * k + 2]));

        // Fold this column's X into the per-gaussian coefficients.
        const float b1 = fmaf(cc, X, ce);
        const float b0 = fmaf(fmaf(ca, X, cd), X, cf);

        sA[k] = make_float4(b0, b1, cb, c0);
        sB[k] = make_float2(c1, c2);
    }
    __syncthreads();

    float den = 0.f, R = 0.f, G = 0.f, B = 0.f;

    #pragma unroll 8
    for (int k = 0; k < KG; ++k) {
        const float4 q = sA[k];      // b0 b1 cb c0
        const float2 r = sB[k];      // c1 c2

        const float e = fmaf(fmaf(q.z, Y, q.y), Y, q.x);  // (cb*Y+b1)*Y+b0
        const float w = __builtin_amdgcn_exp2f(e);

        den += w;
        R = fmaf(w, q.w, R);
        G = fmaf(w, r.x, G);
        B = fmaf(w, r.y, B);
    }

    const float inv = 1.0f / (den + EPSF);
    out[3 * pix + 0] = fminf(fmaxf(R * inv, 0.f), 1.f);
    out[3 * pix + 1] = fminf(fmaxf(G * inv, 0.f), 1.f);
    out[3 * pix + 2] = fminf(fmaxf(B * inv, 0.f), 1.f);
}

extern "C" void kernel_launch(void* const* d_in, const int* in_sizes, int n_in,
                              void* d_out, int out_size, void* d_ws, size_t ws_size,
                              hipStream_t stream) {
    const float* grid         = (const float*)d_in[0];
    const float* mu           = (const float*)d_in[1];
    const float* log_scales   = (const float*)d_in[2];
    const float* theta        = (const float*)d_in[3];
    const float* color_logits = (const float*)d_in[4];
    const float* log_amp      = (const float*)d_in[5];
    float* out = (float*)d_out;

    const int threads = 512;                 // one column per block
    const int blocks  = HH;                  // 512 blocks -> 4 waves/SIMD
    hipLaunchKernelGGL(gauss_render, dim3(blocks), dim3(threads), 0, stream,
                       grid, mu, log_scales, theta, color_logits, log_amp, out);
}